// Round 2
// baseline (345.315 us; speedup 1.0000x reference)
//
#include <hip/hip_runtime.h>

#define EPS 1e-6f

typedef unsigned short u16;
typedef u16   u16x4  __attribute__((ext_vector_type(4)));
typedef u16   u16x8  __attribute__((ext_vector_type(8)));
typedef float f32x4  __attribute__((ext_vector_type(4)));
typedef short s16x8  __attribute__((ext_vector_type(8)));   // 8 bf16 as raw i16 (4 VGPRs)

enum { BR_LIN = 0, BR_R6, BR_R5, BR_MIN, BR_R3, BR_XY, BR_R1, BR_R0 };

// ---------------- helpers ----------------
__device__ __forceinline__ u16 f2bf(float f) { return __builtin_bit_cast(u16, (__bf16)f); }
__device__ __forceinline__ float bf2f(u16 b) { return (float)__builtin_bit_cast(__bf16, b); }

__device__ __forceinline__ s16x8 lds_bf8(const u16* p) {
  u16x8 r = *(const u16x8*)p;
  return __builtin_bit_cast(s16x8, r);
}

__device__ __forceinline__ f32x4 mfma16(s16x8 a, s16x8 b, f32x4 c) {
  return __builtin_amdgcn_mfma_f32_16x16x32_bf16(a, b, c, 0, 0, 0);
}

__device__ __forceinline__ float r_poly_f(float a) {
  float d  = 0.5f - a;
  float d2 = d * d;
  float num = 0.25f + 1.65811f * d + 2.15388f * d2 + 8.2844f * d2 * d + 6.16764f * d2 * d2;
  float den = a * (1.0f - a);
  if (fabsf(den) < EPS) den = EPS;
  return num / den;
}

// generalized power mean (w0*X^r + w1*Y^r)^(1/r); rinv = 1/r precomputed
__device__ __forceinline__ float pmean(float X, float Y, float r, float rinv, float w0, float w1) {
  float tx = exp2f(r * log2f(X));
  float ty = exp2f(r * log2f(Y));
  float s  = w0 * tx + w1 * ty;
  return exp2f(rinv * log2f(s));
}

// one combine step; params p[8] per node (branch chosen on uniform per-node `a`)
__device__ __forceinline__ float combine_step(float carry, float leaf, const float* p) {
  float w0 = p[0], w1 = p[1], a_fb = p[2];
  float c0 = p[3], c1 = p[4], c2 = p[5], c3 = p[6];
  int meta = __float_as_int(p[7]);
  int br = meta & 0xff, flip = meta >> 8;

  float xx = carry, yy = leaf;
  xx = __builtin_isnan(xx) ? EPS : xx;
  yy = __builtin_isnan(yy) ? EPS : yy;
  xx = fminf(fmaxf(xx, EPS), 1.0f - EPS);
  yy = fminf(fmaxf(yy, EPS), 1.0f - EPS);
  float X = flip ? (1.0f - xx) : xx;
  float Y = flip ? (1.0f - yy) : yy;

  float r;
  switch (br) {
    default:
    case BR_LIN: r = w0 * X + w1 * Y; break;
    case BR_R6:  r = c0 * (w0 * X + w1 * Y) + c1 * pmean(X, Y, c2, c3, w0, w1); break;
    case BR_R5:  r = pmean(X, Y, c0, c1, w0, w1); break;
    case BR_MIN: r = fminf(X, Y); break;
    case BR_R3:  r = 4.0f * (c0 * fminf(X, Y) + c1 * (X * Y)); break;
    case BR_XY:  r = X * Y; break;
    case BR_R1:  r = exp2f(c0 * log2f(X * Y)); break;
    case BR_R0:  r = (fabsf(X - 1.0f) < EPS && fabsf(Y - 1.0f) < EPS) ? 1.0f : 0.0f; break;
  }
  if (flip) r = 1.0f - r;
  if (__builtin_isnan(r)) r = a_fb;
  return r;
}

// ---------------- kernel 1: per-node chain params ----------------
__global__ void param_kernel(const float* __restrict__ W, const float* __restrict__ Bv,
                             float* __restrict__ prm, int n) {
  int i = blockIdx.x * blockDim.x + threadIdx.x;
  if (i >= n) return;
  float w0r = W[2 * i], w1r = W[2 * i + 1];
  float m  = fmaxf(w0r, w1r);
  float e0 = expf(w0r - m), e1 = expf(w1r - m);
  float inv = 1.0f / (e0 + e1);
  float w0 = e0 * inv, w1 = e1 * inv;

  float b   = Bv[i];
  float sig = 1.0f / (1.0f + expf(-b));
  float a_fb = sig * 3.0f - 1.0f;            // raw a_scaled (NaN fallback value)

  float a = a_fb;
  if (__builtin_isnan(a)) a = -1.0f;
  a = fminf(fmaxf(a, -1.0f + EPS), 2.0f - EPS);
  int flip = (a < 0.5f - EPS) ? 1 : 0;
  float aa = a;
  if (flip) aa = fminf(fmaxf(1.0f - a, -1.0f + EPS), 2.0f - EPS);

  // priority (last-where-wins): R0 > R1 > XY > R3 > MIN > R5 > R6 > LIN
  int br; float c0 = 0.f, c1 = 0.f, c2 = 0.f, c3 = 0.f;
  if (fabsf(aa - 2.0f) < EPS) br = BR_R0;
  else if (aa > 1.25f && aa < 2.0f) {
    br = BR_R1;
    c0 = sqrtf(fmaxf(3.0f / fmaxf(2.0f - aa, EPS) - 1.0f, EPS));
  } else if (fabsf(aa - 1.25f) < EPS) br = BR_XY;
  else if (aa > 1.0f && aa < 1.25f) { br = BR_R3; c0 = 1.25f - aa; c1 = aa - 1.0f; }
  else if (fabsf(aa - 1.0f) < EPS) br = BR_MIN;
  else if (aa >= 0.75f && aa < 1.0f) {
    br = BR_R5;
    float ac = fminf(fmaxf(aa, 0.75f), 1.0f - EPS);
    float ra = r_poly_f(ac);
    if (fabsf(ra) < EPS) ra = EPS;
    c0 = ra; c1 = 1.0f / ra;
  } else if (aa > 0.5f && aa < 0.75f) {
    br = BR_R6;
    c0 = 3.0f - 4.0f * aa; c1 = 4.0f * aa - 2.0f;
    float R = r_poly_f(0.75f);
    if (fabsf(R) < EPS) R = EPS;
    c2 = R; c3 = 1.0f / R;
  } else br = BR_LIN;

  float* o = prm + i * 8;
  o[0] = w0; o[1] = w1; o[2] = a_fb; o[3] = c0; o[4] = c1; o[5] = c2; o[6] = c3;
  o[7] = __int_as_float(br | (flip << 8));
}

// ---------------- kernel 2: Sinkhorn via scaling vectors ----------------
// alpha = 1/(E beta); beta = 1/(E^T alpha); P = diag(alpha) E diag(beta)
// Writes PT[l][k] = P[k][l] split into bf16 hi/lo.
__global__ __launch_bounds__(1024) void sinkhorn_kernel(
    const float* __restrict__ logits, float* __restrict__ E, float* __restrict__ ET,
    u16* __restrict__ PTh, u16* __restrict__ PTl, int use_ws) {
  __shared__ float alpha[256], beta[256], psum[1024];
  const int t = threadIdx.x;
  const int i = t >> 2;
  const int base = (t & 3) << 6;

  if (t < 256) beta[t] = 1.0f;
  if (use_ws) {
    for (int e = 0; e < 64; ++e) {
      float v = expf(logits[i * 256 + base + e]);
      E[i * 256 + base + e]    = v;
      ET[(base + e) * 256 + i] = v;
    }
  }
  __syncthreads();

  for (int it = 0; it < 10; ++it) {
    // row: alpha = 1/(E beta)
    float s = 0.f;
    if (use_ws) {
      for (int e = 0; e < 64; e += 4) {
        f32x4 ev = *(const f32x4*)(E + i * 256 + base + e);
        f32x4 bv = *(const f32x4*)(beta + base + e);
        s += ev[0] * bv[0] + ev[1] * bv[1] + ev[2] * bv[2] + ev[3] * bv[3];
      }
    } else {
      for (int e = 0; e < 64; ++e)
        s += expf(logits[i * 256 + base + e]) * beta[base + e];
    }
    psum[t] = s;
    __syncthreads();
    if (t < 256)
      alpha[t] = 1.0f / (psum[t << 2] + psum[(t << 2) + 1] + psum[(t << 2) + 2] + psum[(t << 2) + 3]);
    __syncthreads();
    // col: beta = 1/(E^T alpha)
    s = 0.f;
    if (use_ws) {
      for (int e = 0; e < 64; e += 4) {
        f32x4 ev = *(const f32x4*)(ET + i * 256 + base + e);
        f32x4 av = *(const f32x4*)(alpha + base + e);
        s += ev[0] * av[0] + ev[1] * av[1] + ev[2] * av[2] + ev[3] * av[3];
      }
    } else {
      for (int e = 0; e < 64; ++e)
        s += expf(logits[(base + e) * 256 + i]) * alpha[base + e];
    }
    psum[t] = s;
    __syncthreads();
    if (t < 256)
      beta[t] = 1.0f / (psum[t << 2] + psum[(t << 2) + 1] + psum[(t << 2) + 2] + psum[(t << 2) + 3]);
    __syncthreads();
  }

  // write PT (l = i, k-chunk = base): PT[l][k] = alpha[k]*E[k][l]*beta[l]
  float bi = beta[i];
  for (int e = 0; e < 64; e += 4) {
    int k = base + e;
    u16x4 vh, vl;
    #pragma unroll
    for (int j2 = 0; j2 < 4; ++j2) {
      float ev;
      if (use_ws) ev = ET[i * 256 + k + j2];
      else        ev = expf(logits[(k + j2) * 256 + i]);
      float pv = alpha[k + j2] * ev * bi;
      u16 h = f2bf(pv);
      vh[j2] = h;
      vl[j2] = f2bf(pv - bf2f(h));
    }
    *(u16x4*)(PTh + i * 256 + k) = vh;
    *(u16x4*)(PTl + i * 256 + k) = vl;
  }
}

// ---------------- kernel 3: fused split-bf16 MFMA GEMM + chain ----------------
// Block: 256 threads (4 waves), b-tile = 128, full L=256, K staged 32 at a time.
// C[m=l][n=b]; wave w owns b in [32w,32w+32) (2 N-frags), all 16 M-frags.
#define BSTR 40   // LDS row stride (u16 elems) for 32-k staging tiles
#define CSTR 140  // LDS row stride (f32) for chain transpose buffer

__global__ __launch_bounds__(256, 2) void gemm_chain_kernel(
    const float* __restrict__ x, const u16* __restrict__ PTh, const u16* __restrict__ PTl,
    const float* __restrict__ prm, float* __restrict__ out) {
  __shared__ __align__(16) char smem[61440];
  u16* xs_h = (u16*)smem;            // [128][BSTR]
  u16* xs_l = xs_h + 128 * BSTR;
  u16* pt_h = xs_l + 128 * BSTR;     // [256][BSTR]
  u16* pt_l = pt_h + 256 * BSTR;
  float* cbuf = (float*)smem;        // [64][CSTR]  (aliases staging, used after GEMM)
  float* cprm = cbuf + 64 * CSTR;    // 2040 floats

  const int t    = threadIdx.x;
  const int w    = t >> 6;
  const int lane = t & 63;
  const int bl   = lane & 15;
  const int kh   = lane >> 4;
  const int b0   = blockIdx.x * 128;

  f32x4 acc[16][2];
  #pragma unroll
  for (int m = 0; m < 16; ++m) {
    acc[m][0] = f32x4{0.f, 0.f, 0.f, 0.f};
    acc[m][1] = f32x4{0.f, 0.f, 0.f, 0.f};
  }

  for (int kc = 0; kc < 8; ++kc) {
    // stage x tile [128 b][32 k] -> bf16 hi/lo
    #pragma unroll
    for (int j = 0; j < 4; ++j) {
      int idx = t + (j << 8);        // 1024 float4s
      int bb = idx >> 3, c4 = idx & 7;
      f32x4 v = *(const f32x4*)(x + (b0 + bb) * 256 + (kc << 5) + (c4 << 2));
      u16x4 vh, vl;
      #pragma unroll
      for (int e = 0; e < 4; ++e) {
        float f = v[e];
        u16 h = f2bf(f);
        vh[e] = h;
        vl[e] = f2bf(f - bf2f(h));
      }
      *(u16x4*)(xs_h + bb * BSTR + (c4 << 2)) = vh;
      *(u16x4*)(xs_l + bb * BSTR + (c4 << 2)) = vl;
    }
    // stage PT tile [256 l][32 k] hi/lo
    #pragma unroll
    for (int j = 0; j < 8; ++j) {
      int idx = t + (j << 8);        // 2048 u16x4s
      int ll = idx >> 3, c4 = idx & 7;
      *(u16x4*)(pt_h + ll * BSTR + (c4 << 2)) = *(const u16x4*)(PTh + ll * 256 + (kc << 5) + (c4 << 2));
      *(u16x4*)(pt_l + ll * BSTR + (c4 << 2)) = *(const u16x4*)(PTl + ll * 256 + (kc << 5) + (c4 << 2));
    }
    __syncthreads();

    s16x8 bh[2], blo[2];
    #pragma unroll
    for (int nf = 0; nf < 2; ++nf) {
      int brow = (w << 5) + (nf << 4) + bl;
      bh[nf]  = lds_bf8(xs_h + brow * BSTR + (kh << 3));
      blo[nf] = lds_bf8(xs_l + brow * BSTR + (kh << 3));
    }
    #pragma unroll
    for (int mf = 0; mf < 16; ++mf) {
      int arow = (mf << 4) + bl;
      s16x8 ah = lds_bf8(pt_h + arow * BSTR + (kh << 3));
      s16x8 al = lds_bf8(pt_l + arow * BSTR + (kh << 3));
      #pragma unroll
      for (int nf = 0; nf < 2; ++nf) {
        acc[mf][nf] = mfma16(ah, bh[nf],  acc[mf][nf]);
        acc[mf][nf] = mfma16(ah, blo[nf], acc[mf][nf]);
        acc[mf][nf] = mfma16(al, bh[nf],  acc[mf][nf]);
      }
    }
    __syncthreads();
  }

  // load chain params into LDS (aliases dead staging area; visible after next barrier)
  for (int j = t; j < 2040; j += 256) cprm[j] = prm[j];

  float carry = 0.0f;
  const int cb   = (w << 5) + (lane & 31);
  const bool act = (lane < 32);

  #pragma unroll
  for (int c = 0; c < 4; ++c) {
    __syncthreads();
    // dump l-chunk [64c, 64c+64) of acc into cbuf[l'][b]
    #pragma unroll
    for (int d = 0; d < 4; ++d) {
      int mf = (c << 2) + d;
      #pragma unroll
      for (int nf = 0; nf < 2; ++nf) {
        #pragma unroll
        for (int r = 0; r < 4; ++r) {
          int lr = (d << 4) + (kh << 2) + r;           // row within chunk
          int bc = (w << 5) + (nf << 4) + bl;          // b within tile
          cbuf[lr * CSTR + bc] = acc[mf][nf][r];
        }
      }
    }
    __syncthreads();
    if (act) {
      for (int lc = 0; lc < 64; ++lc) {
        float v = cbuf[lc * CSTR + cb];
        int l = (c << 6) + lc;
        carry = (l == 0) ? v : combine_step(carry, v, cprm + ((l - 1) << 3));
      }
    }
  }
  if (act) out[b0 + cb] = carry;
}

// ---------------- launch ----------------
extern "C" void kernel_launch(void* const* d_in, const int* in_sizes, int n_in,
                              void* d_out, int out_size, void* d_ws, size_t ws_size,
                              hipStream_t stream) {
  const float* x       = (const float*)d_in[0];   // (65536, 256)
  const float* logits  = (const float*)d_in[1];   // (256, 256)
  const float* weights = (const float*)d_in[2];   // (255, 2)
  const float* biases  = (const float*)d_in[3];   // (255,)
  float* out = (float*)d_out;                     // (65536, 1)

  char* ws = (char*)d_ws;
  u16*   PTh = (u16*)ws;                          // 131072 B
  u16*   PTl = (u16*)(ws + 131072);               // 131072 B
  float* prm = (float*)(ws + 262144);             // 8160 B
  float* E   = (float*)(ws + 270336);             // 262144 B
  float* ET  = (float*)(ws + 532480);             // 262144 B
  int use_ws = (ws_size >= 794624) ? 1 : 0;

  int Btot = in_sizes[0] / 256;                   // 65536

  param_kernel<<<1, 256, 0, stream>>>(weights, biases, prm, 255);
  sinkhorn_kernel<<<1, 1024, 0, stream>>>(logits, E, ET, PTh, PTl, use_ws);
  gemm_chain_kernel<<<Btot / 128, 256, 0, stream>>>(x, PTh, PTl, prm, out);
}

// Round 3
// 143.474 us; speedup vs baseline: 2.4068x; 2.4068x over previous
//
#include <hip/hip_runtime.h>

#define EPS 1e-6f

typedef unsigned short u16;
typedef u16   u16x4  __attribute__((ext_vector_type(4)));
typedef u16   u16x8  __attribute__((ext_vector_type(8)));
typedef float f32x4  __attribute__((ext_vector_type(4)));
typedef short s16x8  __attribute__((ext_vector_type(8)));   // 8 bf16 as raw i16 (4 VGPRs)

enum { BR_LIN = 0, BR_R6, BR_R5, BR_MIN, BR_R3, BR_XY, BR_R1, BR_R0 };

// ---------------- helpers ----------------
__device__ __forceinline__ u16 f2bf(float f) { return __builtin_bit_cast(u16, (__bf16)f); }
__device__ __forceinline__ float bf2f(u16 b) { return (float)__builtin_bit_cast(__bf16, b); }

__device__ __forceinline__ s16x8 lds_bf8(const u16* p) {
  u16x8 r = *(const u16x8*)p;
  return __builtin_bit_cast(s16x8, r);
}

__device__ __forceinline__ f32x4 mfma16(s16x8 a, s16x8 b, f32x4 c) {
  return __builtin_amdgcn_mfma_f32_16x16x32_bf16(a, b, c, 0, 0, 0);
}

__device__ __forceinline__ float r_poly_f(float a) {
  float d  = 0.5f - a;
  float d2 = d * d;
  float num = 0.25f + 1.65811f * d + 2.15388f * d2 + 8.2844f * d2 * d + 6.16764f * d2 * d2;
  float den = a * (1.0f - a);
  if (fabsf(den) < EPS) den = EPS;
  return num / den;
}

// generalized power mean (w0*X^r + w1*Y^r)^(1/r); rinv = 1/r precomputed
__device__ __forceinline__ float pmean(float X, float Y, float r, float rinv, float w0, float w1) {
  float tx = exp2f(r * log2f(X));
  float ty = exp2f(r * log2f(Y));
  float s  = w0 * tx + w1 * ty;
  return exp2f(rinv * log2f(s));
}

// one combine step; params p[8] per node (branch chosen on uniform per-node `a`)
__device__ __forceinline__ float combine_step(float carry, float leaf, const float* p) {
  float w0 = p[0], w1 = p[1], a_fb = p[2];
  float c0 = p[3], c1 = p[4], c2 = p[5], c3 = p[6];
  int meta = __float_as_int(p[7]);
  int br = meta & 0xff, flip = meta >> 8;

  float xx = carry, yy = leaf;
  xx = __builtin_isnan(xx) ? EPS : xx;
  yy = __builtin_isnan(yy) ? EPS : yy;
  xx = fminf(fmaxf(xx, EPS), 1.0f - EPS);
  yy = fminf(fmaxf(yy, EPS), 1.0f - EPS);
  float X = flip ? (1.0f - xx) : xx;
  float Y = flip ? (1.0f - yy) : yy;

  float r;
  switch (br) {
    default:
    case BR_LIN: r = w0 * X + w1 * Y; break;
    case BR_R6:  r = c0 * (w0 * X + w1 * Y) + c1 * pmean(X, Y, c2, c3, w0, w1); break;
    case BR_R5:  r = pmean(X, Y, c0, c1, w0, w1); break;
    case BR_MIN: r = fminf(X, Y); break;
    case BR_R3:  r = 4.0f * (c0 * fminf(X, Y) + c1 * (X * Y)); break;
    case BR_XY:  r = X * Y; break;
    case BR_R1:  r = exp2f(c0 * log2f(X * Y)); break;
    case BR_R0:  r = (fabsf(X - 1.0f) < EPS && fabsf(Y - 1.0f) < EPS) ? 1.0f : 0.0f; break;
  }
  if (flip) r = 1.0f - r;
  if (__builtin_isnan(r)) r = a_fb;
  return r;
}

// ---------------- kernel 1: per-node chain params ----------------
__global__ void param_kernel(const float* __restrict__ W, const float* __restrict__ Bv,
                             float* __restrict__ prm, int n) {
  int i = blockIdx.x * blockDim.x + threadIdx.x;
  if (i >= n) return;
  float w0r = W[2 * i], w1r = W[2 * i + 1];
  float m  = fmaxf(w0r, w1r);
  float e0 = expf(w0r - m), e1 = expf(w1r - m);
  float inv = 1.0f / (e0 + e1);
  float w0 = e0 * inv, w1 = e1 * inv;

  float b   = Bv[i];
  float sig = 1.0f / (1.0f + expf(-b));
  float a_fb = sig * 3.0f - 1.0f;            // raw a_scaled (NaN fallback value)

  float a = a_fb;
  if (__builtin_isnan(a)) a = -1.0f;
  a = fminf(fmaxf(a, -1.0f + EPS), 2.0f - EPS);
  int flip = (a < 0.5f - EPS) ? 1 : 0;
  float aa = a;
  if (flip) aa = fminf(fmaxf(1.0f - a, -1.0f + EPS), 2.0f - EPS);

  // priority (last-where-wins): R0 > R1 > XY > R3 > MIN > R5 > R6 > LIN
  int br; float c0 = 0.f, c1 = 0.f, c2 = 0.f, c3 = 0.f;
  if (fabsf(aa - 2.0f) < EPS) br = BR_R0;
  else if (aa > 1.25f && aa < 2.0f) {
    br = BR_R1;
    c0 = sqrtf(fmaxf(3.0f / fmaxf(2.0f - aa, EPS) - 1.0f, EPS));
  } else if (fabsf(aa - 1.25f) < EPS) br = BR_XY;
  else if (aa > 1.0f && aa < 1.25f) { br = BR_R3; c0 = 1.25f - aa; c1 = aa - 1.0f; }
  else if (fabsf(aa - 1.0f) < EPS) br = BR_MIN;
  else if (aa >= 0.75f && aa < 1.0f) {
    br = BR_R5;
    float ac = fminf(fmaxf(aa, 0.75f), 1.0f - EPS);
    float ra = r_poly_f(ac);
    if (fabsf(ra) < EPS) ra = EPS;
    c0 = ra; c1 = 1.0f / ra;
  } else if (aa > 0.5f && aa < 0.75f) {
    br = BR_R6;
    c0 = 3.0f - 4.0f * aa; c1 = 4.0f * aa - 2.0f;
    float R = r_poly_f(0.75f);
    if (fabsf(R) < EPS) R = EPS;
    c2 = R; c3 = 1.0f / R;
  } else br = BR_LIN;

  float* o = prm + i * 8;
  o[0] = w0; o[1] = w1; o[2] = a_fb; o[3] = c0; o[4] = c1; o[5] = c2; o[6] = c3;
  o[7] = __int_as_float(br | (flip << 8));
}

// ---------------- kernel 2: register-resident Sinkhorn ----------------
// E = exp(logits) lives entirely in VGPRs: thread (R,C) (R=t>>5, C=t&31)
// holds e[dr][m] = E[8R+dr][C+32m], dr,m in [0,8).
// alpha = 1/(E beta); beta = 1/(E^T alpha); P = diag(alpha) E diag(beta).
// LDS psum stride 33 => all partial writes/reads bank-conflict-free.
__global__ __launch_bounds__(1024, 4) void sinkhorn_kernel(
    const float* __restrict__ logits,
    u16* __restrict__ PTh, u16* __restrict__ PTl) {
  __shared__ float alpha[256], beta[256];
  __shared__ float psum[256][33];

  const int t  = threadIdx.x;
  const int R  = t >> 5;        // 0..31: row block (rows 8R..8R+7)
  const int C  = t & 31;        // 0..31: col residue (cols C+32m)
  const int r0 = R << 3;

  // load E block into registers (coalesced: lane C reads col C+32m)
  float e[8][8];
  #pragma unroll
  for (int dr = 0; dr < 8; ++dr) {
    const float* row = logits + (r0 + dr) * 256 + C;
    #pragma unroll
    for (int m = 0; m < 8; ++m) e[dr][m] = __expf(row[m << 5]);
  }

  if (t < 256) beta[t] = 1.0f;
  __syncthreads();

  for (int it = 0; it < 10; ++it) {
    // ---- row pass: alpha = 1/(E beta) ----
    {
      float bv[8], acc[8];
      #pragma unroll
      for (int m = 0; m < 8; ++m) bv[m] = beta[C + (m << 5)];
      #pragma unroll
      for (int dr = 0; dr < 8; ++dr) {
        float s = 0.f;
        #pragma unroll
        for (int m = 0; m < 8; ++m) s += e[dr][m] * bv[m];
        acc[dr] = s;
      }
      #pragma unroll
      for (int dr = 0; dr < 8; ++dr) psum[r0 + dr][C] = acc[dr];
    }
    __syncthreads();
    if (t < 256) {
      float s = 0.f;
      #pragma unroll
      for (int j = 0; j < 32; ++j) s += psum[t][j];
      alpha[t] = 1.0f / s;
    }
    __syncthreads();
    // ---- col pass: beta = 1/(E^T alpha) ----
    {
      float av[8], acc[8];
      #pragma unroll
      for (int dr = 0; dr < 8; ++dr) av[dr] = alpha[r0 + dr];   // broadcast
      #pragma unroll
      for (int m = 0; m < 8; ++m) {
        float s = 0.f;
        #pragma unroll
        for (int dr = 0; dr < 8; ++dr) s += e[dr][m] * av[dr];
        acc[m] = s;
      }
      #pragma unroll
      for (int m = 0; m < 8; ++m) psum[C + (m << 5)][R] = acc[m];
    }
    __syncthreads();
    if (t < 256) {
      float s = 0.f;
      #pragma unroll
      for (int j = 0; j < 32; ++j) s += psum[t][j];
      beta[t] = 1.0f / s;
    }
    __syncthreads();
  }

  // ---- writeout: PT[l][k] = alpha[k]*E[k][l]*beta[l], split bf16 hi/lo ----
  float av[8], bv[8];
  #pragma unroll
  for (int dr = 0; dr < 8; ++dr) av[dr] = alpha[r0 + dr];
  #pragma unroll
  for (int m = 0; m < 8; ++m) bv[m] = beta[C + (m << 5)];

  #pragma unroll
  for (int m = 0; m < 8; ++m) {
    int l = C + (m << 5);
    u16x8 vh, vl;
    #pragma unroll
    for (int dr = 0; dr < 8; ++dr) {
      float pv = av[dr] * e[dr][m] * bv[m];
      u16 h = f2bf(pv);
      vh[dr] = h;
      vl[dr] = f2bf(pv - bf2f(h));
    }
    *(u16x8*)(PTh + l * 256 + r0) = vh;
    *(u16x8*)(PTl + l * 256 + r0) = vl;
  }
}

// ---------------- kernel 3: fused split-bf16 MFMA GEMM + chain ----------------
// Block: 256 threads (4 waves), b-tile = 128, full L=256, K staged 32 at a time.
// C[m=l][n=b]; wave w owns b in [32w,32w+32) (2 N-frags), all 16 M-frags.
#define BSTR 40   // LDS row stride (u16 elems) for 32-k staging tiles
#define CSTR 140  // LDS row stride (f32) for chain transpose buffer

__global__ __launch_bounds__(256, 2) void gemm_chain_kernel(
    const float* __restrict__ x, const u16* __restrict__ PTh, const u16* __restrict__ PTl,
    const float* __restrict__ prm, float* __restrict__ out) {
  __shared__ __align__(16) char smem[61440];
  u16* xs_h = (u16*)smem;            // [128][BSTR]
  u16* xs_l = xs_h + 128 * BSTR;
  u16* pt_h = xs_l + 128 * BSTR;     // [256][BSTR]
  u16* pt_l = pt_h + 256 * BSTR;
  float* cbuf = (float*)smem;        // [64][CSTR]  (aliases staging, used after GEMM)
  float* cprm = cbuf + 64 * CSTR;    // 2040 floats

  const int t    = threadIdx.x;
  const int w    = t >> 6;
  const int lane = t & 63;
  const int bl   = lane & 15;
  const int kh   = lane >> 4;
  const int b0   = blockIdx.x * 128;

  f32x4 acc[16][2];
  #pragma unroll
  for (int m = 0; m < 16; ++m) {
    acc[m][0] = f32x4{0.f, 0.f, 0.f, 0.f};
    acc[m][1] = f32x4{0.f, 0.f, 0.f, 0.f};
  }

  for (int kc = 0; kc < 8; ++kc) {
    // stage x tile [128 b][32 k] -> bf16 hi/lo
    #pragma unroll
    for (int j = 0; j < 4; ++j) {
      int idx = t + (j << 8);        // 1024 float4s
      int bb = idx >> 3, c4 = idx & 7;
      f32x4 v = *(const f32x4*)(x + (b0 + bb) * 256 + (kc << 5) + (c4 << 2));
      u16x4 vh, vl;
      #pragma unroll
      for (int e = 0; e < 4; ++e) {
        float f = v[e];
        u16 h = f2bf(f);
        vh[e] = h;
        vl[e] = f2bf(f - bf2f(h));
      }
      *(u16x4*)(xs_h + bb * BSTR + (c4 << 2)) = vh;
      *(u16x4*)(xs_l + bb * BSTR + (c4 << 2)) = vl;
    }
    // stage PT tile [256 l][32 k] hi/lo
    #pragma unroll
    for (int j = 0; j < 8; ++j) {
      int idx = t + (j << 8);        // 2048 u16x4s
      int ll = idx >> 3, c4 = idx & 7;
      *(u16x4*)(pt_h + ll * BSTR + (c4 << 2)) = *(const u16x4*)(PTh + ll * 256 + (kc << 5) + (c4 << 2));
      *(u16x4*)(pt_l + ll * BSTR + (c4 << 2)) = *(const u16x4*)(PTl + ll * 256 + (kc << 5) + (c4 << 2));
    }
    __syncthreads();

    s16x8 bh[2], blo[2];
    #pragma unroll
    for (int nf = 0; nf < 2; ++nf) {
      int brow = (w << 5) + (nf << 4) + bl;
      bh[nf]  = lds_bf8(xs_h + brow * BSTR + (kh << 3));
      blo[nf] = lds_bf8(xs_l + brow * BSTR + (kh << 3));
    }
    #pragma unroll
    for (int mf = 0; mf < 16; ++mf) {
      int arow = (mf << 4) + bl;
      s16x8 ah = lds_bf8(pt_h + arow * BSTR + (kh << 3));
      s16x8 al = lds_bf8(pt_l + arow * BSTR + (kh << 3));
      #pragma unroll
      for (int nf = 0; nf < 2; ++nf) {
        acc[mf][nf] = mfma16(ah, bh[nf],  acc[mf][nf]);
        acc[mf][nf] = mfma16(ah, blo[nf], acc[mf][nf]);
        acc[mf][nf] = mfma16(al, bh[nf],  acc[mf][nf]);
      }
    }
    __syncthreads();
  }

  // load chain params into LDS (aliases dead staging area; visible after next barrier)
  for (int j = t; j < 2040; j += 256) cprm[j] = prm[j];

  float carry = 0.0f;
  const int cb   = (w << 5) + (lane & 31);
  const bool act = (lane < 32);

  #pragma unroll
  for (int c = 0; c < 4; ++c) {
    __syncthreads();
    // dump l-chunk [64c, 64c+64) of acc into cbuf[l'][b]
    #pragma unroll
    for (int d = 0; d < 4; ++d) {
      int mf = (c << 2) + d;
      #pragma unroll
      for (int nf = 0; nf < 2; ++nf) {
        #pragma unroll
        for (int r = 0; r < 4; ++r) {
          int lr = (d << 4) + (kh << 2) + r;           // row within chunk
          int bc = (w << 5) + (nf << 4) + bl;          // b within tile
          cbuf[lr * CSTR + bc] = acc[mf][nf][r];
        }
      }
    }
    __syncthreads();
    if (act) {
      for (int lc = 0; lc < 64; ++lc) {
        float v = cbuf[lc * CSTR + cb];
        int l = (c << 6) + lc;
        carry = (l == 0) ? v : combine_step(carry, v, cprm + ((l - 1) << 3));
      }
    }
  }
  if (act) out[b0 + cb] = carry;
}

// ---------------- launch ----------------
extern "C" void kernel_launch(void* const* d_in, const int* in_sizes, int n_in,
                              void* d_out, int out_size, void* d_ws, size_t ws_size,
                              hipStream_t stream) {
  const float* x       = (const float*)d_in[0];   // (65536, 256)
  const float* logits  = (const float*)d_in[1];   // (256, 256)
  const float* weights = (const float*)d_in[2];   // (255, 2)
  const float* biases  = (const float*)d_in[3];   // (255,)
  float* out = (float*)d_out;                     // (65536, 1)

  char* ws = (char*)d_ws;
  u16*   PTh = (u16*)ws;                          // 131072 B
  u16*   PTl = (u16*)(ws + 131072);               // 131072 B
  float* prm = (float*)(ws + 262144);             // 8160 B

  int Btot = in_sizes[0] / 256;                   // 65536

  param_kernel<<<1, 256, 0, stream>>>(weights, biases, prm, 255);
  sinkhorn_kernel<<<1, 1024, 0, stream>>>(logits, PTh, PTl);
  gemm_chain_kernel<<<Btot / 128, 256, 0, stream>>>(x, PTh, PTl, prm, out);
}

// Round 4
// 128.753 us; speedup vs baseline: 2.6820x; 1.1143x over previous
//
#include <hip/hip_runtime.h>

#define EPS 1e-6f

typedef unsigned short u16;
typedef u16   u16x4  __attribute__((ext_vector_type(4)));
typedef u16   u16x8  __attribute__((ext_vector_type(8)));
typedef float f32x4  __attribute__((ext_vector_type(4)));
typedef short s16x8  __attribute__((ext_vector_type(8)));   // 8 bf16 as raw i16 (4 VGPRs)

enum { BR_LIN = 0, BR_R6, BR_R5, BR_MIN, BR_R3, BR_XY, BR_R1, BR_R0 };

// ---------------- helpers ----------------
__device__ __forceinline__ u16 f2bf(float f) { return __builtin_bit_cast(u16, (__bf16)f); }
__device__ __forceinline__ float bf2f(u16 b) { return (float)__builtin_bit_cast(__bf16, b); }

__device__ __forceinline__ s16x8 lds_bf8(const u16* p) {
  u16x8 r = *(const u16x8*)p;
  return __builtin_bit_cast(s16x8, r);
}

__device__ __forceinline__ f32x4 mfma16(s16x8 a, s16x8 b, f32x4 c) {
  return __builtin_amdgcn_mfma_f32_16x16x32_bf16(a, b, c, 0, 0, 0);
}

__device__ __forceinline__ float r_poly_f(float a) {
  float d  = 0.5f - a;
  float d2 = d * d;
  float num = 0.25f + 1.65811f * d + 2.15388f * d2 + 8.2844f * d2 * d + 6.16764f * d2 * d2;
  float den = a * (1.0f - a);
  if (fabsf(den) < EPS) den = EPS;
  return num / den;
}

__device__ __forceinline__ float pmean(float X, float Y, float r, float rinv, float w0, float w1) {
  float tx = exp2f(r * log2f(X));
  float ty = exp2f(r * log2f(Y));
  float s  = w0 * tx + w1 * ty;
  return exp2f(rinv * log2f(s));
}

__device__ __forceinline__ float combine_step(float carry, float leaf, const float* p) {
  float w0 = p[0], w1 = p[1], a_fb = p[2];
  float c0 = p[3], c1 = p[4], c2 = p[5], c3 = p[6];
  int meta = __float_as_int(p[7]);
  int br = meta & 0xff, flip = meta >> 8;

  float xx = carry, yy = leaf;
  xx = __builtin_isnan(xx) ? EPS : xx;
  yy = __builtin_isnan(yy) ? EPS : yy;
  xx = fminf(fmaxf(xx, EPS), 1.0f - EPS);
  yy = fminf(fmaxf(yy, EPS), 1.0f - EPS);
  float X = flip ? (1.0f - xx) : xx;
  float Y = flip ? (1.0f - yy) : yy;

  float r;
  switch (br) {
    default:
    case BR_LIN: r = w0 * X + w1 * Y; break;
    case BR_R6:  r = c0 * (w0 * X + w1 * Y) + c1 * pmean(X, Y, c2, c3, w0, w1); break;
    case BR_R5:  r = pmean(X, Y, c0, c1, w0, w1); break;
    case BR_MIN: r = fminf(X, Y); break;
    case BR_R3:  r = 4.0f * (c0 * fminf(X, Y) + c1 * (X * Y)); break;
    case BR_XY:  r = X * Y; break;
    case BR_R1:  r = exp2f(c0 * log2f(X * Y)); break;
    case BR_R0:  r = (fabsf(X - 1.0f) < EPS && fabsf(Y - 1.0f) < EPS) ? 1.0f : 0.0f; break;
  }
  if (flip) r = 1.0f - r;
  if (__builtin_isnan(r)) r = a_fb;
  return r;
}

// ---------------- kernel 1: per-node chain params ----------------
__global__ void param_kernel(const float* __restrict__ W, const float* __restrict__ Bv,
                             float* __restrict__ prm, int n) {
  int i = blockIdx.x * blockDim.x + threadIdx.x;
  if (i >= n) return;
  float w0r = W[2 * i], w1r = W[2 * i + 1];
  float m  = fmaxf(w0r, w1r);
  float e0 = expf(w0r - m), e1 = expf(w1r - m);
  float inv = 1.0f / (e0 + e1);
  float w0 = e0 * inv, w1 = e1 * inv;

  float b   = Bv[i];
  float sig = 1.0f / (1.0f + expf(-b));
  float a_fb = sig * 3.0f - 1.0f;

  float a = a_fb;
  if (__builtin_isnan(a)) a = -1.0f;
  a = fminf(fmaxf(a, -1.0f + EPS), 2.0f - EPS);
  int flip = (a < 0.5f - EPS) ? 1 : 0;
  float aa = a;
  if (flip) aa = fminf(fmaxf(1.0f - a, -1.0f + EPS), 2.0f - EPS);

  int br; float c0 = 0.f, c1 = 0.f, c2 = 0.f, c3 = 0.f;
  if (fabsf(aa - 2.0f) < EPS) br = BR_R0;
  else if (aa > 1.25f && aa < 2.0f) {
    br = BR_R1;
    c0 = sqrtf(fmaxf(3.0f / fmaxf(2.0f - aa, EPS) - 1.0f, EPS));
  } else if (fabsf(aa - 1.25f) < EPS) br = BR_XY;
  else if (aa > 1.0f && aa < 1.25f) { br = BR_R3; c0 = 1.25f - aa; c1 = aa - 1.0f; }
  else if (fabsf(aa - 1.0f) < EPS) br = BR_MIN;
  else if (aa >= 0.75f && aa < 1.0f) {
    br = BR_R5;
    float ac = fminf(fmaxf(aa, 0.75f), 1.0f - EPS);
    float ra = r_poly_f(ac);
    if (fabsf(ra) < EPS) ra = EPS;
    c0 = ra; c1 = 1.0f / ra;
  } else if (aa > 0.5f && aa < 0.75f) {
    br = BR_R6;
    c0 = 3.0f - 4.0f * aa; c1 = 4.0f * aa - 2.0f;
    float R = r_poly_f(0.75f);
    if (fabsf(R) < EPS) R = EPS;
    c2 = R; c3 = 1.0f / R;
  } else br = BR_LIN;

  float* o = prm + i * 8;
  o[0] = w0; o[1] = w1; o[2] = a_fb; o[3] = c0; o[4] = c1; o[5] = c2; o[6] = c3;
  o[7] = __int_as_float(br | (flip << 8));
}

// ---------------- kernel 2: register-resident Sinkhorn ----------------
__global__ __launch_bounds__(1024, 4) void sinkhorn_kernel(
    const float* __restrict__ logits,
    u16* __restrict__ PTh, u16* __restrict__ PTl) {
  __shared__ float alpha[256], beta[256];
  __shared__ float psum[256][33];

  const int t  = threadIdx.x;
  const int R  = t >> 5;
  const int C  = t & 31;
  const int r0 = R << 3;

  float e[8][8];
  #pragma unroll
  for (int dr = 0; dr < 8; ++dr) {
    const float* row = logits + (r0 + dr) * 256 + C;
    #pragma unroll
    for (int m = 0; m < 8; ++m) e[dr][m] = __expf(row[m << 5]);
  }

  if (t < 256) beta[t] = 1.0f;
  __syncthreads();

  for (int it = 0; it < 10; ++it) {
    {
      float bv[8], acc[8];
      #pragma unroll
      for (int m = 0; m < 8; ++m) bv[m] = beta[C + (m << 5)];
      #pragma unroll
      for (int dr = 0; dr < 8; ++dr) {
        float s = 0.f;
        #pragma unroll
        for (int m = 0; m < 8; ++m) s += e[dr][m] * bv[m];
        acc[dr] = s;
      }
      #pragma unroll
      for (int dr = 0; dr < 8; ++dr) psum[r0 + dr][C] = acc[dr];
    }
    __syncthreads();
    if (t < 256) {
      float s = 0.f;
      #pragma unroll
      for (int j = 0; j < 32; ++j) s += psum[t][j];
      alpha[t] = 1.0f / s;
    }
    __syncthreads();
    {
      float av[8], acc[8];
      #pragma unroll
      for (int dr = 0; dr < 8; ++dr) av[dr] = alpha[r0 + dr];
      #pragma unroll
      for (int m = 0; m < 8; ++m) {
        float s = 0.f;
        #pragma unroll
        for (int dr = 0; dr < 8; ++dr) s += e[dr][m] * av[dr];
        acc[m] = s;
      }
      #pragma unroll
      for (int m = 0; m < 8; ++m) psum[C + (m << 5)][R] = acc[m];
    }
    __syncthreads();
    if (t < 256) {
      float s = 0.f;
      #pragma unroll
      for (int j = 0; j < 32; ++j) s += psum[t][j];
      beta[t] = 1.0f / s;
    }
    __syncthreads();
  }

  float av[8], bv[8];
  #pragma unroll
  for (int dr = 0; dr < 8; ++dr) av[dr] = alpha[r0 + dr];
  #pragma unroll
  for (int m = 0; m < 8; ++m) bv[m] = beta[C + (m << 5)];

  #pragma unroll
  for (int m = 0; m < 8; ++m) {
    int l = C + (m << 5);
    u16x8 vh, vl;
    #pragma unroll
    for (int dr = 0; dr < 8; ++dr) {
      float pv = av[dr] * e[dr][m] * bv[m];
      u16 h = f2bf(pv);
      vh[dr] = h;
      vl[dr] = f2bf(pv - bf2f(h));
    }
    *(u16x8*)(PTh + l * 256 + r0) = vh;
    *(u16x8*)(PTl + l * 256 + r0) = vl;
  }
}

// ---------------- kernel 3: fused split-bf16 MFMA GEMM + chain ----------------
// 512 threads = 8 waves in 2M x 4N grid. b-tile = 128, full L = 256, K-step 32.
// Wave (wm,wn): mf' in [0,8) -> rows l = (wm*8+mf')*16..+16 ; nf' in [0,2):
// cols b = (wn*2+nf')*16..+16. acc[8][2] f32x4 = 64 VGPR.
// LDS (48KB): xs_h[128][32]u16 @0, xs_l @8K, pt_h[256][32]u16 @16K, pt_l @32K.
// Epilogue aliases: cbuf(64 x CSTR f32) @0, cprm(2040 f32) @36864.
#define CSTR 132

__global__ __launch_bounds__(512, 4) void gemm_chain_kernel(
    const float* __restrict__ x, const u16* __restrict__ PTh, const u16* __restrict__ PTl,
    const float* __restrict__ prm, float* __restrict__ out) {
  __shared__ __align__(16) char smem[49152];
  u16* xs_h = (u16*)smem;                       // [128][32]
  u16* xs_l = (u16*)(smem + 8192);
  u16* pt_h = (u16*)(smem + 16384);             // [256][32]
  u16* pt_l = (u16*)(smem + 32768);
  float* cbuf = (float*)smem;                   // [64][CSTR] = 33792 B
  float* cprm = (float*)(smem + 36864);         // 8160 B

  const int t    = threadIdx.x;
  const int w    = t >> 6;
  const int lane = t & 63;
  const int bl   = lane & 15;
  const int kh   = lane >> 4;
  const int wm   = w >> 2;                      // 0..1
  const int wn   = w & 3;                       // 0..3
  const int b0   = blockIdx.x * 128;

  // staging thread mapping
  const int xrow = t >> 3;                      // 0..63 (rows xrow, xrow+64)
  const int xc4  = t & 7;                       // float4 within 32-float slice
  const int prow = t >> 2;                      // PT row base (rows prow, prow+128)
  const int pk   = t & 3;                       // u16x8 within 32-u16 slice

  f32x4 acc[8][2];
  #pragma unroll
  for (int m = 0; m < 8; ++m) {
    acc[m][0] = f32x4{0.f, 0.f, 0.f, 0.f};
    acc[m][1] = f32x4{0.f, 0.f, 0.f, 0.f};
  }

  // prefetch registers
  f32x4 xr[2];
  u16x8 ph[2], pl[2];

  // ---- prologue: prefetch tile 0 ----
  #pragma unroll
  for (int j = 0; j < 2; ++j) {
    xr[j] = *(const f32x4*)(x + (b0 + xrow + 64 * j) * 256 + (xc4 << 2));
    ph[j] = *(const u16x8*)(PTh + (prow + 128 * j) * 256 + (pk << 3));
    pl[j] = *(const u16x8*)(PTl + (prow + 128 * j) * 256 + (pk << 3));
  }

  for (int kc = 0; kc < 8; ++kc) {
    // ---- W phase: write prefetched tile to LDS ----
    #pragma unroll
    for (int j = 0; j < 2; ++j) {
      u16x4 vh, vl;
      #pragma unroll
      for (int e = 0; e < 4; ++e) {
        float f = xr[j][e];
        u16 h = f2bf(f);
        vh[e] = h;
        vl[e] = f2bf(f - bf2f(h));
      }
      *(u16x4*)(xs_h + (xrow + 64 * j) * 32 + (xc4 << 2)) = vh;
      *(u16x4*)(xs_l + (xrow + 64 * j) * 32 + (xc4 << 2)) = vl;
      // PT: LDS destination is linear in chunk id (t + 512j)
      *(u16x8*)(pt_h + ((t + 512 * j) << 3)) = ph[j];
      *(u16x8*)(pt_l + ((t + 512 * j) << 3)) = pl[j];
    }
    __syncthreads();

    // ---- issue prefetch for next tile (hidden under MFMA phase) ----
    if (kc < 7) {
      int k1 = (kc + 1) << 5;
      #pragma unroll
      for (int j = 0; j < 2; ++j) {
        xr[j] = *(const f32x4*)(x + (b0 + xrow + 64 * j) * 256 + k1 + (xc4 << 2));
        ph[j] = *(const u16x8*)(PTh + (prow + 128 * j) * 256 + k1 + (pk << 3));
        pl[j] = *(const u16x8*)(PTl + (prow + 128 * j) * 256 + k1 + (pk << 3));
      }
    }

    // ---- C phase: fragments + MFMA ----
    s16x8 bh[2], blo[2];
    #pragma unroll
    for (int nf = 0; nf < 2; ++nf) {
      int brow = ((wn << 1) + nf) * 16 + bl;
      bh[nf]  = lds_bf8(xs_h + brow * 32 + (kh << 3));
      blo[nf] = lds_bf8(xs_l + brow * 32 + (kh << 3));
    }
    #pragma unroll
    for (int mf = 0; mf < 8; ++mf) {
      int arow = ((wm << 3) + mf) * 16 + bl;
      s16x8 ah = lds_bf8(pt_h + arow * 32 + (kh << 3));
      s16x8 al = lds_bf8(pt_l + arow * 32 + (kh << 3));
      #pragma unroll
      for (int nf = 0; nf < 2; ++nf) {
        acc[mf][nf] = mfma16(ah, bh[nf],  acc[mf][nf]);
        acc[mf][nf] = mfma16(ah, blo[nf], acc[mf][nf]);
        acc[mf][nf] = mfma16(al, bh[nf],  acc[mf][nf]);
      }
    }
    __syncthreads();
  }

  // ---- chain params into LDS (region disjoint from cbuf) ----
  for (int j = t; j < 2040; j += 512) cprm[j] = prm[j];

  float carry = 0.0f;

  #pragma unroll
  for (int c = 0; c < 4; ++c) {
    __syncthreads();
    // waves with wm == c>>1 dump l-chunk [64c, 64c+64) into cbuf[l'][b]
    if (wm == (c >> 1)) {
      #pragma unroll
      for (int d = 0; d < 4; ++d) {
        int mf = ((c & 1) << 2) + d;
        #pragma unroll
        for (int nf = 0; nf < 2; ++nf) {
          int bc = (wn << 5) + (nf << 4) + bl;
          #pragma unroll
          for (int r = 0; r < 4; ++r) {
            int lr = (d << 4) + (kh << 2) + r;
            cbuf[lr * CSTR + bc] = acc[mf][nf][r];
          }
        }
      }
    }
    __syncthreads();
    if (t < 128) {
      for (int lc = 0; lc < 64; ++lc) {
        float v = cbuf[lc * CSTR + t];
        int l = (c << 6) + lc;
        carry = (l == 0) ? v : combine_step(carry, v, cprm + ((l - 1) << 3));
      }
    }
  }
  if (t < 128) out[b0 + t] = carry;
}

// ---------------- launch ----------------
extern "C" void kernel_launch(void* const* d_in, const int* in_sizes, int n_in,
                              void* d_out, int out_size, void* d_ws, size_t ws_size,
                              hipStream_t stream) {
  const float* x       = (const float*)d_in[0];   // (65536, 256)
  const float* logits  = (const float*)d_in[1];   // (256, 256)
  const float* weights = (const float*)d_in[2];   // (255, 2)
  const float* biases  = (const float*)d_in[3];   // (255,)
  float* out = (float*)d_out;                     // (65536, 1)

  char* ws = (char*)d_ws;
  u16*   PTh = (u16*)ws;                          // 131072 B
  u16*   PTl = (u16*)(ws + 131072);               // 131072 B
  float* prm = (float*)(ws + 262144);             // 8160 B

  int Btot = in_sizes[0] / 256;                   // 65536

  param_kernel<<<1, 256, 0, stream>>>(weights, biases, prm, 255);
  sinkhorn_kernel<<<1, 1024, 0, stream>>>(logits, PTh, PTl);
  gemm_chain_kernel<<<Btot / 128, 512, 0, stream>>>(x, PTh, PTl, prm, out);
}